// Round 9
// baseline (5268.270 us; speedup 1.0000x reference)
//
#include <hip/hip_runtime.h>
#include <hip/hip_bf16.h>

// LSTM: T=8192, IN=3000, H=100 (4H=400), torch gate order i,f,g,o.
// Phase 1: xg[T][400] = input @ w_ih^T + (b_ih+b_hh), written PERMUTED:
//          column 4u+g  <-  original column u+100g  (unit-major gate packing)
// Phase 2: single-workgroup scan, 256 threads / 4 waves, MFMA-based:
//   w_hh rows permuted to R=4u+g; K padded 100->128; M=400 -> 25 tiles of 16,
//   split 7/6/6/6 across waves. A-fragments pinned in PHYSICAL AGPRs a0..a111.
//   B = h (f16, LDS, double-buffered) broadcast to 16 cols; D layout
//   (col=lane&15, row=4*(lane>>4)+reg) gives lane 16q+col all 4 gates of
//   unit 4*(tb+col)+q in its 4 acc regs -> in-lane elementwise, 1 barrier/step.
// ROUND-9 FIX vs R8 (1388 cyc/step): TILE4 issued each acc's 4 MFMAs
// back-to-back -> 7 serialized dependency chains (~560 cyc stall). Now MFMAs
// are K-step-major interleaved (acc0..acc6 per ks): each acc's next MFMA is
// 7 issues (~35 cyc) away, hiding dependent latency. xg is folded into the
// MFMA C-operand (acc init = x_cur; off-diagonal columns discarded).

#define GBM 128
#define GBN 128
#define GBK 16

typedef _Float16 h2_t  __attribute__((ext_vector_type(2)));
typedef _Float16 f16x8 __attribute__((ext_vector_type(8)));
typedef float    f32x4 __attribute__((ext_vector_type(4)));

__global__ __launch_bounds__(256) void gates_gemm(
    const float* __restrict__ A,    // [T][IN]
    const float* __restrict__ W,    // [FH][IN]
    const float* __restrict__ bih,  // [FH]
    const float* __restrict__ bhh,  // [FH]
    float* __restrict__ XG,         // [T][FH]  (permuted columns)
    int T, int IN, int FH)
{
    __shared__ __align__(16) float As[GBK][GBM];
    __shared__ __align__(16) float Bs[GBK][GBN];
    const int bm = blockIdx.x * GBM;
    const int bn = blockIdx.y * GBN;
    const int tid = (int)threadIdx.x;
    const int tx = tid & 15, ty = tid >> 4;
    const int H = FH >> 2;   // 100

    float acc[8][8];
    #pragma unroll
    for (int i = 0; i < 8; ++i)
        #pragma unroll
        for (int j = 0; j < 8; ++j) acc[i][j] = 0.f;

    for (int k0 = 0; k0 < IN; k0 += GBK) {
        __syncthreads();
        #pragma unroll
        for (int q = 0; q < 2; ++q) {
            int idx = tid + q * 256;
            int row = idx >> 2;
            int kq  = (idx & 3) << 2;
            int gk  = k0 + kq;
            float4 av = make_float4(0.f, 0.f, 0.f, 0.f);
            float4 bv = make_float4(0.f, 0.f, 0.f, 0.f);
            if (gk < IN) {
                av = *(const float4*)&A[(size_t)(bm + row) * IN + gk];
                if (bn + row < FH)
                    bv = *(const float4*)&W[(size_t)(bn + row) * IN + gk];
            }
            As[kq + 0][row] = av.x; As[kq + 1][row] = av.y;
            As[kq + 2][row] = av.z; As[kq + 3][row] = av.w;
            Bs[kq + 0][row] = bv.x; Bs[kq + 1][row] = bv.y;
            Bs[kq + 2][row] = bv.z; Bs[kq + 3][row] = bv.w;
        }
        __syncthreads();
        #pragma unroll
        for (int kk = 0; kk < GBK; ++kk) {
            float4 a0 = *(const float4*)&As[kk][ty * 4];
            float4 a1 = *(const float4*)&As[kk][64 + ty * 4];
            float4 b0 = *(const float4*)&Bs[kk][tx * 4];
            float4 b1 = *(const float4*)&Bs[kk][64 + tx * 4];
            float am[8] = {a0.x, a0.y, a0.z, a0.w, a1.x, a1.y, a1.z, a1.w};
            float bn_[8] = {b0.x, b0.y, b0.z, b0.w, b1.x, b1.y, b1.z, b1.w};
            #pragma unroll
            for (int i = 0; i < 8; ++i)
                #pragma unroll
                for (int j = 0; j < 8; ++j)
                    acc[i][j] = fmaf(am[i], bn_[j], acc[i][j]);
        }
    }

    #pragma unroll
    for (int i = 0; i < 8; ++i) {
        int r = bm + ((i < 4) ? (ty * 4 + i) : (64 + ty * 4 + (i - 4)));
        #pragma unroll
        for (int j = 0; j < 8; ++j) {
            int cidx = bn + ((j < 4) ? (tx * 4 + j) : (64 + tx * 4 + (j - 4)));
            if (cidx < FH) {
                int pc = 4 * (cidx % H) + cidx / H;   // unit-major permutation
                XG[(size_t)r * FH + pc] = acc[i][j] + bih[cidx] + bhh[cidx];
            }
        }
    }
}

__device__ __forceinline__ float sigmoid_fast(float x) {
    return 1.f / (1.f + __expf(-x));
}
__device__ __forceinline__ float tanh_fast(float x) {
    return 1.f - 2.f / (__expf(2.f * x) + 1.f);
}

// pack W[k], W[k+1] (f32) into one dword of two f16 (zero past K=100)
__device__ __forceinline__ float pack_pair(const float* rp, int k) {
    float a = 0.f, b = 0.f;
    if (k < 100) { a = rp[k]; b = rp[k + 1]; }
    h2_t p = {(_Float16)a, (_Float16)b};
    return __builtin_bit_cast(float, p);
}

#define ACLOB \
    "a0","a1","a2","a3","a4","a5","a6","a7","a8","a9","a10","a11","a12","a13",\
    "a14","a15","a16","a17","a18","a19","a20","a21","a22","a23","a24","a25",\
    "a26","a27","a28","a29","a30","a31","a32","a33","a34","a35","a36","a37",\
    "a38","a39","a40","a41","a42","a43","a44","a45","a46","a47","a48","a49",\
    "a50","a51","a52","a53","a54","a55","a56","a57","a58","a59","a60","a61",\
    "a62","a63","a64","a65","a66","a67","a68","a69","a70","a71","a72","a73",\
    "a74","a75","a76","a77","a78","a79","a80","a81","a82","a83","a84","a85",\
    "a86","a87","a88","a89","a90","a91","a92","a93","a94","a95","a96","a97",\
    "a98","a99","a100","a101","a102","a103","a104","a105","a106","a107",\
    "a108","a109","a110","a111"

#define WRW(N, V) \
    asm volatile("v_accvgpr_write_b32 a" #N ", %0" :: "v"(V) : "a" #N)

#define LF(m, ks, N0, N1, N2, N3) { \
    const int kb_ = 32 * (ks) + 8 * q; \
    WRW(N0, pack_pair(rowp[m], kb_ + 0)); \
    WRW(N1, pack_pair(rowp[m], kb_ + 2)); \
    WRW(N2, pack_pair(rowp[m], kb_ + 4)); \
    WRW(N3, pack_pair(rowp[m], kb_ + 6)); }

#define MF(ACC, AR, B) \
    asm volatile("v_mfma_f32_16x16x32_f16 %0, " AR ", %1, %0" \
                 : "+v"(ACC) : "v"(B) : ACLOB)

__global__ __launch_bounds__(256, 1) void lstm_scan_mfma(
    const float* __restrict__ XGp,   // [T][400] permuted (4u+g)
    const float* __restrict__ Whh,   // [400][100] original layout
    const float* __restrict__ wlin,  // [100]
    const float* __restrict__ blin,  // [1]
    float* __restrict__ out, int T)
{
    __shared__ __align__(16) _Float16 hbuf[2][128];  // h (f16), K-padded
    __shared__ float hfin[100];
    const int tid = (int)threadIdx.x;
    const int w   = tid >> 6;        // wave 0..3
    const int l   = tid & 63;
    const int q   = l >> 4;          // row-group / k-block 0..3
    const int col = l & 15;          // MFMA column = tile selector
    const int NT  = (w == 0) ? 7 : 6;
    const int tb  = (w == 0) ? 0 : 7 + 6 * (w - 1);   // 0,7,13,19

    // per-lane weight row pointers for this wave's 7 tile slots
    const float* rowp[7];
    #pragma unroll
    for (int m = 0; m < 7; ++m) {
        int mg = tb + m; if (mg > 24) mg = 24;        // clamp pad tile
        int R  = 16 * mg + col;                       // permuted row 4u+g
        rowp[m] = Whh + (size_t)((R >> 2) + 100 * (R & 3)) * 100;
    }

    // ---- load A-fragments into PHYSICAL AGPRs a0..a111 (once) ----
    LF(0,0,  0,  1,  2,  3)  LF(0,1,  4,  5,  6,  7)
    LF(0,2,  8,  9, 10, 11)  LF(0,3, 12, 13, 14, 15)
    LF(1,0, 16, 17, 18, 19)  LF(1,1, 20, 21, 22, 23)
    LF(1,2, 24, 25, 26, 27)  LF(1,3, 28, 29, 30, 31)
    LF(2,0, 32, 33, 34, 35)  LF(2,1, 36, 37, 38, 39)
    LF(2,2, 40, 41, 42, 43)  LF(2,3, 44, 45, 46, 47)
    LF(3,0, 48, 49, 50, 51)  LF(3,1, 52, 53, 54, 55)
    LF(3,2, 56, 57, 58, 59)  LF(3,3, 60, 61, 62, 63)
    LF(4,0, 64, 65, 66, 67)  LF(4,1, 68, 69, 70, 71)
    LF(4,2, 72, 73, 74, 75)  LF(4,3, 76, 77, 78, 79)
    LF(5,0, 80, 81, 82, 83)  LF(5,1, 84, 85, 86, 87)
    LF(5,2, 88, 89, 90, 91)  LF(5,3, 92, 93, 94, 95)
    LF(6,0, 96, 97, 98, 99)  LF(6,1,100,101,102,103)
    LF(6,2,104,105,106,107)  LF(6,3,108,109,110,111)

    if (tid < 128) {
        hbuf[0][tid] = (_Float16)0.f;
        hbuf[1][tid] = (_Float16)0.f;
    }

    // elementwise lane mapping: lane 16q+col handles unit 4*(tb+col)+q
    const bool act = (col < NT);
    const int  u   = act ? (4 * (tb + col) + q) : 0;

    // depth-2 xg prefetch (per-lane float4 = 4 gates of unit u)
    f32x4 x_cur = *(const f32x4*)(XGp + 4 * u);
    f32x4 x_nxt = *(const f32x4*)(XGp + (size_t)(T > 1 ? 1 : 0) * 400 + 4 * u);

    float c = 0.f, hlast = 0.f;
    __syncthreads();

    int cur = 0;
    for (int t = 0; t < T; ++t) {
        int tp = (t + 2 < T) ? (t + 2) : (T - 1);
        f32x4 x_new = *(const f32x4*)(XGp + (size_t)tp * 400 + 4 * u);

        // B fragments: h broadcast to all 16 columns; k = 32*ks + 8*q + j
        const _Float16* hb = hbuf[cur];
        f16x8 b0 = *(const f16x8*)(hb +       8 * q);
        f16x8 b1 = *(const f16x8*)(hb +  32 + 8 * q);
        f16x8 b2 = *(const f16x8*)(hb +  64 + 8 * q);
        f16x8 b3 = *(const f16x8*)(hb +  96 + 8 * q);

        // C-in = this lane's xg (valid on the col==m diagonal; other
        // columns' C is discarded by the select below)
        f32x4 acc0 = x_cur, acc1 = x_cur, acc2 = x_cur, acc3 = x_cur;
        f32x4 acc4 = x_cur, acc5 = x_cur, acc6 = x_cur;

        // K-step-major interleave: each acc's next MFMA is 7 issues away,
        // so the dependent-accumulator latency is hidden.
        asm volatile("s_nop 1" ::: );   // VALU acc-init -> MFMA C-read hazard
        MF(acc0, "a[0:3]",   b0); MF(acc1, "a[16:19]", b0);
        MF(acc2, "a[32:35]", b0); MF(acc3, "a[48:51]", b0);
        MF(acc4, "a[64:67]", b0); MF(acc5, "a[80:83]", b0);
        MF(acc6, "a[96:99]", b0);

        MF(acc0, "a[4:7]",   b1); MF(acc1, "a[20:23]", b1);
        MF(acc2, "a[36:39]", b1); MF(acc3, "a[52:55]", b1);
        MF(acc4, "a[68:71]", b1); MF(acc5, "a[84:87]", b1);
        MF(acc6, "a[100:103]", b1);

        MF(acc0, "a[8:11]",  b2); MF(acc1, "a[24:27]", b2);
        MF(acc2, "a[40:43]", b2); MF(acc3, "a[56:59]", b2);
        MF(acc4, "a[72:75]", b2); MF(acc5, "a[88:91]", b2);
        MF(acc6, "a[104:107]", b2);

        MF(acc0, "a[12:15]", b3); MF(acc1, "a[28:31]", b3);
        MF(acc2, "a[44:47]", b3); MF(acc3, "a[60:63]", b3);
        MF(acc4, "a[76:79]", b3); MF(acc5, "a[92:95]", b3);
        MF(acc6, "a[108:111]", b3);

        // ---- hazard guard: no acc may be read before this point ----
        int colg;
        asm volatile("s_nop 7\n\ts_nop 7\n\tv_or_b32 %0, 0, %1"
                     : "=v"(colg) : "v"(col));

        f32x4 g = (colg == 1) ? acc1 : acc0;
        g = (colg == 2) ? acc2 : g;
        g = (colg == 3) ? acc3 : g;
        g = (colg == 4) ? acc4 : g;
        g = (colg == 5) ? acc5 : g;
        g = (colg == 6) ? acc6 : g;

        float iv = sigmoid_fast(g[0]);
        float fv = sigmoid_fast(g[1]);
        float gv = tanh_fast   (g[2]);
        float ov = sigmoid_fast(g[3]);
        c = fv * c + iv * gv;
        float h = ov * tanh_fast(c);
        if (act) {
            hlast = h;
            hbuf[cur ^ 1][u] = (_Float16)h;
        }
        __syncthreads();
        cur ^= 1;
        x_cur = x_nxt; x_nxt = x_new;
    }

    if (act) hfin[u] = hlast * wlin[u];
    __syncthreads();
    if (tid == 0) {
        float s = blin[0];
        for (int k = 0; k < 100; ++k) s += hfin[k];
        out[0] = s;
    }
}

extern "C" void kernel_launch(void* const* d_in, const int* in_sizes, int n_in,
                              void* d_out, int out_size, void* d_ws, size_t ws_size,
                              hipStream_t stream) {
    const float* input = (const float*)d_in[0];  // [T][IN]
    const float* w_ih  = (const float*)d_in[1];  // [4H][IN]
    const float* w_hh  = (const float*)d_in[2];  // [4H][H]
    const float* b_ih  = (const float*)d_in[3];  // [4H]
    const float* b_hh  = (const float*)d_in[4];  // [4H]
    const float* w_lin = (const float*)d_in[5];  // [H]
    const float* b_lin = (const float*)d_in[6];  // [1]
    float* out = (float*)d_out;

    const int FH = in_sizes[3];            // 400
    const int IN = in_sizes[1] / FH;       // 3000
    const int T  = in_sizes[0] / IN;       // 8192

    float* xg = (float*)d_ws;              // [T][FH] = 13.1 MB (permuted)

    dim3 grid((T + GBM - 1) / GBM, (FH + GBN - 1) / GBN);
    gates_gemm<<<grid, 256, 0, stream>>>(input, w_ih, b_ih, b_hh, xg, T, IN, FH);
    lstm_scan_mfma<<<1, 256, 0, stream>>>(xg, w_hh, w_lin, b_lin, out, T);
}